// Round 12
// baseline (419.238 us; speedup 1.0000x reference)
//
#include <hip/hip_runtime.h>
#include <hip/hip_bf16.h>
#include <cstdint>

#define D_IN 512
#define D_HID 128

typedef unsigned short u16;
typedef unsigned int u32;
typedef __attribute__((ext_vector_type(8))) short short8;
typedef __attribute__((ext_vector_type(4))) float f32x4;

__device__ __forceinline__ u16 f2bf(float f) {
    u32 u = __float_as_uint(f);
    u = (u + 0x7FFFu + ((u >> 16) & 1u)) >> 16;
    return (u16)u;
}
__device__ __forceinline__ float bfc(short x) {
    return __uint_as_float(((u32)(u16)x) << 16);
}
__device__ __forceinline__ float bflo(u32 u) { return __uint_as_float(u << 16); }
__device__ __forceinline__ float bfhi(u32 u) { return __uint_as_float(u & 0xFFFF0000u); }

// ================= CSR build =================
__global__ __launch_bounds__(256) void k_deg_int(const int* __restrict__ dst,
                                                 int* __restrict__ deg, int E) {
    int e = blockIdx.x * 256 + threadIdx.x;
    if (e < E) atomicAdd(&deg[dst[e]], 1);
}

__global__ __launch_bounds__(256) void k_scan_block(const int* __restrict__ deg,
                                                    int* __restrict__ rowptr,
                                                    int* __restrict__ bsum, int N) {
    __shared__ int sh[256];
    int i = blockIdx.x * 256 + threadIdx.x;
    int v = (i < N) ? deg[i] : 0;
    sh[threadIdx.x] = v;
    __syncthreads();
#pragma unroll
    for (int off = 1; off < 256; off <<= 1) {
        int t = (threadIdx.x >= off) ? sh[threadIdx.x - off] : 0;
        __syncthreads();
        sh[threadIdx.x] += t;
        __syncthreads();
    }
    int incl = sh[threadIdx.x];
    if (i < N) rowptr[i] = incl - v;
    if (threadIdx.x == 255) bsum[blockIdx.x] = incl;
}

// apply block offsets (re-scanning the P partials locally), init cursor, dinv
__global__ __launch_bounds__(256) void k_apply_offset(int* __restrict__ rowptr,
                                                      const int* __restrict__ bsum,
                                                      int* __restrict__ deg_cursor,
                                                      float* __restrict__ dinv,
                                                      int N, int E, int P) {
    __shared__ int sh[256];
    int v = (threadIdx.x < P) ? bsum[threadIdx.x] : 0;
    sh[threadIdx.x] = v;
    __syncthreads();
#pragma unroll
    for (int off = 1; off < 256; off <<= 1) {
        int t = (threadIdx.x >= off) ? sh[threadIdx.x - off] : 0;
        __syncthreads();
        sh[threadIdx.x] += t;
        __syncthreads();
    }
    int boff = (blockIdx.x == 0) ? 0 : sh[blockIdx.x - 1];
    int i = blockIdx.x * 256 + threadIdx.x;
    if (i == 0) rowptr[N] = E;
    if (i >= N) return;
    int dv = deg_cursor[i];
    int rp = rowptr[i] + boff;
    rowptr[i] = rp;
    deg_cursor[i] = rp;
    dinv[i] = rsqrtf((float)dv + 1.0f);
}

__global__ __launch_bounds__(256) void k_fill_csr(const int* __restrict__ src,
                                                  const int* __restrict__ dst,
                                                  int* __restrict__ cursor,
                                                  int* __restrict__ csr, int E) {
    int e = blockIdx.x * 256 + threadIdx.x;
    if (e >= E) return;
    int pos = atomicAdd(&cursor[dst[e]], 1);
    csr[pos] = src[e];
}

// ============ all weights -> bf16 transposed, one launch ============
__global__ __launch_bounds__(256) void k_wt_all(const float* __restrict__ W1,
                                                const float* __restrict__ W2,
                                                const float* __restrict__ W3,
                                                u16* __restrict__ WT1,
                                                u16* __restrict__ WT2,
                                                u16* __restrict__ WT3) {
    int t = blockIdx.x * 256 + threadIdx.x;
    if (t < 65536) {                       // 128 cols x 512 k
        int c = t >> 9, k = t & 511;
        WT1[t] = f2bf(W1[(size_t)k * 128 + c]);
    } else if (t < 65536 + 16384) {
        int u = t - 65536;
        int c = u >> 7, k = u & 127;
        WT2[u] = f2bf(W2[(size_t)k * 128 + c]);
    } else if (t < 65536 + 32768) {
        int u = t - 65536 - 16384;
        int c = u >> 7, k = u & 127;
        WT3[u] = f2bf(W3[(size_t)k * 128 + c]);
    }
}

// ====== MFMA GEMM: Y = (X @ W) * dinv[row], bf16 out ======
// CHUNKED=false: Y row-major [N][128].  CHUNKED=true: Y chunk-major [4][N][32].
template <int K, typename TI, bool CHUNKED>
__global__ __launch_bounds__(256) void k_gemm_mfma(const TI* __restrict__ X,
                                                   const u16* __restrict__ WT,
                                                   const float* __restrict__ dinv,
                                                   u16* __restrict__ Y, int N) {
    __shared__ u16 Xs[64 * 40];
    __shared__ u16 Ws[128 * 40];
    const int tid = threadIdx.x;
    const int wv = tid >> 6;
    const int lane = tid & 63;
    const int row0 = blockIdx.x * 64;
    const int rsel = lane & 15;
    const int kgrp = (lane >> 4) * 8;

    f32x4 acc[8];
#pragma unroll
    for (int c = 0; c < 8; ++c) acc[c] = (f32x4){0.f, 0.f, 0.f, 0.f};

    for (int k0 = 0; k0 < K; k0 += 32) {
        {
            int r = tid >> 2;
            int kk = (tid & 3) * 8;
            int row = row0 + r;
            if constexpr (sizeof(TI) == 4) {
                float v[8];
                if (row < N) {
                    float4 p0 = *(const float4*)&X[(size_t)row * K + k0 + kk];
                    float4 p1 = *(const float4*)&X[(size_t)row * K + k0 + kk + 4];
                    v[0] = p0.x; v[1] = p0.y; v[2] = p0.z; v[3] = p0.w;
                    v[4] = p1.x; v[5] = p1.y; v[6] = p1.z; v[7] = p1.w;
                } else {
#pragma unroll
                    for (int i = 0; i < 8; ++i) v[i] = 0.f;
                }
                union { u16 us[8]; short8 v8; } tmp;
#pragma unroll
                for (int i = 0; i < 8; ++i) tmp.us[i] = f2bf(v[i]);
                *(short8*)&Xs[r * 40 + kk] = tmp.v8;
            } else {
                short8 v8 = {};
                if (row < N) v8 = *(const short8*)&X[(size_t)row * K + k0 + kk];
                *(short8*)&Xs[r * 40 + kk] = v8;
            }
        }
        {
            int col = tid >> 1;
            int kh = (tid & 1) * 16;
            const u16* g = &WT[(size_t)col * K + k0 + kh];
            u16* d = &Ws[col * 40 + kh];
            *(short8*)d = *(const short8*)g;
            *(short8*)(d + 8) = *(const short8*)(g + 8);
        }
        __syncthreads();
        short8 a = *(const short8*)&Xs[(wv * 16 + rsel) * 40 + kgrp];
#pragma unroll
        for (int c = 0; c < 8; ++c) {
            short8 b = *(const short8*)&Ws[(c * 16 + rsel) * 40 + kgrp];
            acc[c] = __builtin_amdgcn_mfma_f32_16x16x32_bf16(a, b, acc[c], 0, 0, 0);
        }
        __syncthreads();
    }
    // D layout: col = c*16 + rsel, row = (lane>>4)*4 + reg ; scale by dinv[row]
#pragma unroll
    for (int r = 0; r < 4; ++r) {
        int row = row0 + wv * 16 + (lane >> 4) * 4 + r;
        if (row < N) {
            float ds = dinv[row];
#pragma unroll
            for (int c = 0; c < 8; ++c) {
                u16 val = f2bf(acc[c][r] * ds);
                if constexpr (CHUNKED) {
                    int col = c * 16 + rsel;
                    Y[((size_t)(col >> 5) * N + row) * 32 + (col & 31)] = val;
                } else {
                    Y[(size_t)row * 128 + c * 16 + rsel] = val;
                }
            }
        }
    }
}

// ===== row-major gather core (pre-scaled XW'): 4 edge-slots x 16 lanes, dwordx4 =====
#define GATHER_CORE(XW, rowptr, csr, node, q, es, a)                               \
    int beg = rowptr[node], end = rowptr[node + 1];                                \
    float a[8];                                                                    \
    _Pragma("unroll") for (int i = 0; i < 8; ++i) a[i] = 0.f;                      \
    {                                                                              \
        int j = beg + es;                                                          \
        for (; j + 12 < end; j += 16) {                                            \
            int s0 = csr[j], s1 = csr[j + 4], s2 = csr[j + 8], s3 = csr[j + 12];   \
            short8 r0 = *(const short8*)&XW[(size_t)s0 * 128 + q * 8];             \
            short8 r1 = *(const short8*)&XW[(size_t)s1 * 128 + q * 8];             \
            short8 r2 = *(const short8*)&XW[(size_t)s2 * 128 + q * 8];             \
            short8 r3 = *(const short8*)&XW[(size_t)s3 * 128 + q * 8];             \
            _Pragma("unroll") for (int i = 0; i < 8; ++i)                          \
                a[i] += (bfc(r0[i]) + bfc(r1[i])) + (bfc(r2[i]) + bfc(r3[i]));     \
        }                                                                          \
        if (j + 4 < end) {                                                         \
            int s0 = csr[j], s1 = csr[j + 4];                                      \
            short8 r0 = *(const short8*)&XW[(size_t)s0 * 128 + q * 8];             \
            short8 r1 = *(const short8*)&XW[(size_t)s1 * 128 + q * 8];             \
            _Pragma("unroll") for (int i = 0; i < 8; ++i)                          \
                a[i] += bfc(r0[i]) + bfc(r1[i]);                                   \
            j += 8;                                                                \
        }                                                                          \
        if (j < end) {                                                             \
            int s = csr[j];                                                        \
            short8 r = *(const short8*)&XW[(size_t)s * 128 + q * 8];               \
            _Pragma("unroll") for (int i = 0; i < 8; ++i) a[i] += bfc(r[i]);       \
        }                                                                          \
    }                                                                              \
    _Pragma("unroll") for (int i = 0; i < 8; ++i) {                                \
        a[i] += __shfl_xor(a[i], 16);                                              \
        a[i] += __shfl_xor(a[i], 32);                                              \
    }

// ===== layer 1: gather + self + bias + LN + ReLU -> H bf16 (row-major) =====
__global__ __launch_bounds__(256) void k_gather_ln_relu(const u16* __restrict__ XW,
                                                        const int* __restrict__ rowptr,
                                                        const int* __restrict__ csr,
                                                        const float* __restrict__ dinv,
                                                        const float* __restrict__ b,
                                                        const float* __restrict__ gamma,
                                                        const float* __restrict__ beta,
                                                        u16* __restrict__ H, int N) {
    int node = blockIdx.x * 4 + (threadIdx.x >> 6);
    int lane = threadIdx.x & 63;
    int q = lane & 15;
    int es = lane >> 4;
    if (node >= N) return;
    float di = dinv[node];
    GATHER_CORE(XW, rowptr, csr, node, q, es, a)
    short8 us = *(const short8*)&XW[(size_t)node * 128 + q * 8];
    float4 b0 = *(const float4*)&b[q * 8];
    float4 b1 = *(const float4*)&b[q * 8 + 4];
    float v[8];
#pragma unroll
    for (int i = 0; i < 8; ++i) {
        float bb = (i < 4) ? ((const float*)&b0)[i] : ((const float*)&b1)[i - 4];
        v[i] = (a[i] + bfc(us[i])) * di + bb;
    }
    float s = 0.f, sq = 0.f;
#pragma unroll
    for (int i = 0; i < 8; ++i) { s += v[i]; sq += v[i] * v[i]; }
#pragma unroll
    for (int off = 8; off; off >>= 1) {
        s  += __shfl_xor(s, off);
        sq += __shfl_xor(sq, off);
    }
    float mu  = s * (1.f / 128.f);
    float var = sq * (1.f / 128.f) - mu * mu;
    float rr  = rsqrtf(var + 1e-5f);
    float4 g0 = *(const float4*)&gamma[q * 8];
    float4 g1 = *(const float4*)&gamma[q * 8 + 4];
    float4 e0 = *(const float4*)&beta[q * 8];
    float4 e1 = *(const float4*)&beta[q * 8 + 4];
    if (es == 0) {
        union { u16 us[8]; short8 v8; } o;
#pragma unroll
        for (int i = 0; i < 8; ++i) {
            float gg = (i < 4) ? ((const float*)&g0)[i] : ((const float*)&g1)[i - 4];
            float ee = (i < 4) ? ((const float*)&e0)[i] : ((const float*)&e1)[i - 4];
            o.us[i] = f2bf(fmaxf((v[i] - mu) * rr * gg + ee, 0.f));
        }
        *(short8*)&H[(size_t)node * 128 + q * 8] = o.v8;
    }
}

// ===== layer 2 (EXPERIMENT): chunked gather + self + bias + ReLU -> H row-major =====
// XWc layout [4][N][32]; chunk = blockIdx & 3 pins each chunk to XCDs {c, c+4}
// (round-robin block->XCD), 3.2 MB footprint -> L2-resident.
__global__ __launch_bounds__(256) void k_gather_relu_ch(const u16* __restrict__ XWc,
                                                        const int* __restrict__ rowptr,
                                                        const int* __restrict__ csr,
                                                        const float* __restrict__ dinv,
                                                        const float* __restrict__ b,
                                                        u16* __restrict__ H, int N) {
    int bid = blockIdx.x;
    int chunk = bid & 3;
    int node = ((bid >> 2) << 2) + (threadIdx.x >> 6);
    int lane = threadIdx.x & 63;
    int q = lane & 15;           // feature pair q*2, q*2+1 within chunk
    int es = lane >> 4;
    if (node >= N) return;
    float di = dinv[node];
    const u16* XW = XWc + (size_t)chunk * N * 32;
    int beg = rowptr[node], end = rowptr[node + 1];
    float a0 = 0.f, a1 = 0.f;
    {
        int j = beg + es;
        for (; j + 12 < end; j += 16) {
            int s0 = csr[j], s1 = csr[j + 4], s2 = csr[j + 8], s3 = csr[j + 12];
            u32 r0 = *(const u32*)&XW[(size_t)s0 * 32 + q * 2];
            u32 r1 = *(const u32*)&XW[(size_t)s1 * 32 + q * 2];
            u32 r2 = *(const u32*)&XW[(size_t)s2 * 32 + q * 2];
            u32 r3 = *(const u32*)&XW[(size_t)s3 * 32 + q * 2];
            a0 += (bflo(r0) + bflo(r1)) + (bflo(r2) + bflo(r3));
            a1 += (bfhi(r0) + bfhi(r1)) + (bfhi(r2) + bfhi(r3));
        }
        if (j + 4 < end) {
            int s0 = csr[j], s1 = csr[j + 4];
            u32 r0 = *(const u32*)&XW[(size_t)s0 * 32 + q * 2];
            u32 r1 = *(const u32*)&XW[(size_t)s1 * 32 + q * 2];
            a0 += bflo(r0) + bflo(r1);
            a1 += bfhi(r0) + bfhi(r1);
            j += 8;
        }
        if (j < end) {
            int s = csr[j];
            u32 r = *(const u32*)&XW[(size_t)s * 32 + q * 2];
            a0 += bflo(r);
            a1 += bfhi(r);
        }
    }
    a0 += __shfl_xor(a0, 16); a0 += __shfl_xor(a0, 32);
    a1 += __shfl_xor(a1, 16); a1 += __shfl_xor(a1, 32);
    if (es != 0) return;
    u32 us = *(const u32*)&XW[(size_t)node * 32 + q * 2];
    float2 bb = *(const float2*)&b[chunk * 32 + q * 2];
    u32 o0 = f2bf(fmaxf((a0 + bflo(us)) * di + bb.x, 0.f));
    u32 o1 = f2bf(fmaxf((a1 + bfhi(us)) * di + bb.y, 0.f));
    *(u32*)&H[(size_t)node * 128 + chunk * 32 + q * 2] = (o1 << 16) | o0;
}

// ===== layer 3 gather + ReLU fused with layer-4 W4 dot -> XW4' = (h3 . W4) * dinv =====
__global__ __launch_bounds__(256) void k_gather_dot(const u16* __restrict__ XW,
                                                    const int* __restrict__ rowptr,
                                                    const int* __restrict__ csr,
                                                    const float* __restrict__ dinv,
                                                    const float* __restrict__ b,
                                                    const float* __restrict__ W4,
                                                    float* __restrict__ XW4, int N) {
    int node = blockIdx.x * 4 + (threadIdx.x >> 6);
    int lane = threadIdx.x & 63;
    int q = lane & 15;
    int es = lane >> 4;
    if (node >= N) return;
    float di = dinv[node];
    GATHER_CORE(XW, rowptr, csr, node, q, es, a)
    short8 us = *(const short8*)&XW[(size_t)node * 128 + q * 8];
    float4 b0 = *(const float4*)&b[q * 8];
    float4 b1 = *(const float4*)&b[q * 8 + 4];
    float4 w0 = *(const float4*)&W4[q * 8];
    float4 w1 = *(const float4*)&W4[q * 8 + 4];
    float t = 0.f;
#pragma unroll
    for (int i = 0; i < 8; ++i) {
        float bb = (i < 4) ? ((const float*)&b0)[i] : ((const float*)&b1)[i - 4];
        float ww = (i < 4) ? ((const float*)&w0)[i] : ((const float*)&w1)[i - 4];
        float v = fmaxf((a[i] + bfc(us[i])) * di + bb, 0.f);
        t += v * ww;
    }
#pragma unroll
    for (int off = 8; off; off >>= 1) t += __shfl_xor(t, off);
    if (lane == 0) XW4[node] = t * di;     // pre-scaled
}

// ===== final: out = di * (sum_nbrs XW4'[s] + XW4'[node]) + b4 =====
__global__ __launch_bounds__(256) void k_final_scalar(const float* __restrict__ XW4,
                                                      const int* __restrict__ rowptr,
                                                      const int* __restrict__ csr,
                                                      const float* __restrict__ dinv,
                                                      const float* __restrict__ b4,
                                                      float* __restrict__ OUT, int N) {
    int node = blockIdx.x * 16 + (threadIdx.x >> 4);
    int q = threadIdx.x & 15;
    if (node >= N) return;
    int beg = rowptr[node], end = rowptr[node + 1];
    float acc = 0.f;
    for (int j = beg + q; j < end; j += 16) {
        acc += XW4[csr[j]];
    }
#pragma unroll
    for (int off = 8; off; off >>= 1) acc += __shfl_xor(acc, off);
    if (q == 0) {
        OUT[node] = dinv[node] * (acc + XW4[node]) + b4[0];
    }
}

// ================= launch =================
static inline size_t alignup(size_t x) { return (x + 255) & ~(size_t)255; }

extern "C" void kernel_launch(void* const* d_in, const int* in_sizes, int n_in,
                              void* d_out, int out_size, void* d_ws, size_t ws_size,
                              hipStream_t stream) {
    const float* x      = (const float*)d_in[0];
    const float* W1     = (const float*)d_in[1];
    const float* b1     = (const float*)d_in[2];
    const float* gamma1 = (const float*)d_in[3];
    const float* beta1  = (const float*)d_in[4];
    const float* W2     = (const float*)d_in[5];
    const float* b2     = (const float*)d_in[6];
    const float* W3     = (const float*)d_in[7];
    const float* b3     = (const float*)d_in[8];
    const float* W4     = (const float*)d_in[9];
    const float* b4     = (const float*)d_in[10];
    const int*   ei     = (const int*)d_in[11];

    const int N = in_sizes[0] / D_IN;     // 50000
    const int E = in_sizes[11] / 2;       // 625000
    const int* src = ei;
    const int* dst = ei + E;

    char* ws = (char*)d_ws;
    size_t off = 0;
    int*   deg_cur = (int*)(ws + off);   off += alignup((size_t)N * 4);
    int*   rowptr  = (int*)(ws + off);   off += alignup((size_t)(N + 1) * 4);
    int*   bsum    = (int*)(ws + off);   off += alignup(256 * 4);
    float* dinv    = (float*)(ws + off); off += alignup((size_t)N * 4);
    float* xw4     = (float*)(ws + off); off += alignup((size_t)N * 4);
    int*   csr     = (int*)(ws + off);   off += alignup((size_t)E * 4);
    u16*   WT1     = (u16*)(ws + off);   off += alignup((size_t)128 * 512 * 2);
    u16*   WT2     = (u16*)(ws + off);   off += alignup((size_t)128 * 128 * 2);
    u16*   WT3     = (u16*)(ws + off);   off += alignup((size_t)128 * 128 * 2);
    u16*   XW      = (u16*)(ws + off);   off += alignup((size_t)N * 128 * 2);
    u16*   H       = (u16*)(ws + off);

    const int scanBlocks = (N + 255) / 256;   // 196

    // ---- CSR build
    hipMemsetAsync(deg_cur, 0, (size_t)N * 4, stream);
    k_deg_int<<<(E + 255) / 256, 256, 0, stream>>>(dst, deg_cur, E);
    k_scan_block<<<scanBlocks, 256, 0, stream>>>(deg_cur, rowptr, bsum, N);
    k_apply_offset<<<scanBlocks, 256, 0, stream>>>(rowptr, bsum, deg_cur, dinv,
                                                   N, E, scanBlocks);
    k_fill_csr<<<(E + 255) / 256, 256, 0, stream>>>(src, dst, deg_cur, csr, E);

    // ---- weights -> bf16 transposed (single launch)
    k_wt_all<<<(65536 + 32768 + 255) / 256, 256, 0, stream>>>(W1, W2, W3, WT1, WT2, WT3);

    const int gemmGrid   = (N + 63) / 64;
    const int gatherGrid = (N + 3) / 4;
    const int chunkGrid  = ((N + 3) / 4) * 4;   // 4 chunks interleaved in blockIdx

    // ---- Layer 1 (row-major path)
    k_gemm_mfma<512, float, false><<<gemmGrid, 256, 0, stream>>>(x, WT1, dinv, XW, N);
    k_gather_ln_relu<<<gatherGrid, 256, 0, stream>>>(XW, rowptr, csr, dinv,
                                                     b1, gamma1, beta1, H, N);
    // ---- Layer 2 (EXPERIMENT: chunk-major XW2, L2-resident gather)
    k_gemm_mfma<128, u16, true><<<gemmGrid, 256, 0, stream>>>(H, WT2, dinv, XW, N);
    k_gather_relu_ch<<<chunkGrid, 256, 0, stream>>>(XW, rowptr, csr, dinv, b2, H, N);
    // ---- Layer 3 (row-major path, + fused W4 dot)
    k_gemm_mfma<128, u16, false><<<gemmGrid, 256, 0, stream>>>(H, WT3, dinv, XW, N);
    k_gather_dot<<<gatherGrid, 256, 0, stream>>>(XW, rowptr, csr, dinv, b3, W4, xw4, N);
    // ---- Layer 4 aggregate
    k_final_scalar<<<(N + 15) / 16, 256, 0, stream>>>(xw4, rowptr, csr, dinv,
                                                      b4, (float*)d_out, N);
}